// Round 3
// baseline (437.510 us; speedup 1.0000x reference)
//
#include <hip/hip_runtime.h>

typedef __attribute__((ext_vector_type(4))) int int4v;

#define BM 128
#define BN 128
#define BK 64

// ---------------------------------------------------------------------------
// Kernel 0: pack int32 weights (harness passes ALL integer inputs as int32)
// into contiguous int8. w32: [N*K] int32 in [-127,127] -> w8: [N*K] int8.
// Each thread packs 4 values. Memory-bound, ~84 MB traffic ≈ 15 us.
// ---------------------------------------------------------------------------
__global__ __launch_bounds__(256) void pack_w_kernel(const int* __restrict__ w32,
                                                     int* __restrict__ w8,
                                                     long n4) {
    long i = (long)blockIdx.x * 256 + threadIdx.x;  // one per 4 ints
    if (i >= n4) return;
    int4v v = ((const int4v*)w32)[i];
    w8[i] = (v[0] & 0xFF) | ((v[1] & 0xFF) << 8) |
            ((v[2] & 0xFF) << 16) | ((v[3] & 0xFF) << 24);
}

// ---------------------------------------------------------------------------
// Kernel 1: dynamic per-token symmetric int8 quantization.
// x: [T, K] f32  ->  xq: [T, K] i8 (packed), xs: [T] f32 (scale = amax/127)
// One 256-thread block per token.
// ---------------------------------------------------------------------------
template <int NCHUNK>
__global__ __launch_bounds__(256) void quant_kernel(const float* __restrict__ x,
                                                    signed char* __restrict__ xq,
                                                    float* __restrict__ xs,
                                                    int K) {
    const int t = blockIdx.x;
    const int tid = threadIdx.x;
    const float4* row = (const float4*)(x + (size_t)t * K);

    float4 v[NCHUNK];
    float amax = 0.0f;
    #pragma unroll
    for (int i = 0; i < NCHUNK; ++i) {
        float4 f = row[i * 256 + tid];
        v[i] = f;
        amax = fmaxf(amax, fmaxf(fmaxf(fabsf(f.x), fabsf(f.y)),
                                 fmaxf(fabsf(f.z), fabsf(f.w))));
    }
    #pragma unroll
    for (int off = 32; off >= 1; off >>= 1)
        amax = fmaxf(amax, __shfl_xor(amax, off, 64));
    __shared__ float red[4];
    if ((tid & 63) == 0) red[tid >> 6] = amax;
    __syncthreads();
    amax = fmaxf(fmaxf(red[0], red[1]), fmaxf(red[2], red[3]));

    const float scale = fmaxf(amax, 1e-8f) / 127.0f;
    if (tid == 0) xs[t] = scale;
    const float inv = 1.0f / scale;

    int* orow = (int*)(xq + (size_t)t * K);
    #pragma unroll
    for (int i = 0; i < NCHUNK; ++i) {
        float4 f = v[i];
        int q0 = (int)fminf(fmaxf(rintf(f.x * inv), -128.0f), 127.0f);
        int q1 = (int)fminf(fmaxf(rintf(f.y * inv), -128.0f), 127.0f);
        int q2 = (int)fminf(fmaxf(rintf(f.z * inv), -128.0f), 127.0f);
        int q3 = (int)fminf(fmaxf(rintf(f.w * inv), -128.0f), 127.0f);
        orow[i * 256 + tid] =
            (q0 & 0xFF) | ((q1 & 0xFF) << 8) | ((q2 & 0xFF) << 16) | ((q3 & 0xFF) << 24);
    }
}

// ---------------------------------------------------------------------------
// Kernel 2: int8 GEMM (B^T layout) + dequant + bias epilogue.
// A: [M,K] i8 (x_q), B: [N,K] i8 (packed weight_q), C: [M,N] f32.
// 128x128 block tile, BK=64, 4 waves of 64x64 (4x4 of 16x16x64 MFMA).
// global_load_lds(16B) staging into row-major [row][64B] LDS tiles
// (wave-uniform base + lane*16 — verified pattern, cross-checked R1 vs R2).
// Correct for any internal i8-MFMA k-map: A and B fragments use identical
// per-lane byte patterns, so k-pairing is consistent (dot is k-perm invariant).
// ---------------------------------------------------------------------------
__global__ __launch_bounds__(256) void gemm_i8_kernel(
    const signed char* __restrict__ A,
    const signed char* __restrict__ B,
    const float* __restrict__ xs,    // [M] per-token scale
    const float* __restrict__ wsc,   // [N] per-channel weight scale
    const float* __restrict__ bias,  // [N]
    float* __restrict__ C,
    int M, int N, int K) {
    __shared__ __align__(16) signed char sA[BM * BK];
    __shared__ __align__(16) signed char sB[BN * BK];

    const int tid = threadIdx.x;
    const int lane = tid & 63;
    const int wave = tid >> 6;
    const int bm = blockIdx.y * BM;
    const int bn = blockIdx.x * BN;
    const int wm = (wave >> 1) * 64;  // wave's M offset within tile
    const int wn = (wave & 1) * 64;   // wave's N offset within tile

    // Staging: each wave covers 32 rows of A-tile and 32 rows of B-tile
    // (2 x global_load_lds of 16B/lane; 64 lanes = 16 rows x 64B each).
    const signed char* ag = A + (size_t)(bm + wave * 32 + (lane >> 2)) * K + (lane & 3) * 16;
    const signed char* bg = B + (size_t)(bn + wave * 32 + (lane >> 2)) * K + (lane & 3) * 16;
    signed char* la = sA + (wave * 32) * BK;
    signed char* lb = sB + (wave * 32) * BK;

    // Fragment read base: row m = lane&15, 16 contiguous k-bytes at quad*16.
    const int mrow = lane & 15;
    const int ksub = (lane >> 4) * 16;
    const signed char* ra = sA + (size_t)(wm + mrow) * BK + ksub;
    const signed char* rb = sB + (size_t)(wn + mrow) * BK + ksub;

    int4v acc[4][4];
    const int4v zero = {0, 0, 0, 0};
    #pragma unroll
    for (int i = 0; i < 4; ++i)
        #pragma unroll
        for (int j = 0; j < 4; ++j)
            acc[i][j] = zero;

    for (int k0 = 0; k0 < K; k0 += BK) {
        #pragma unroll
        for (int j = 0; j < 2; ++j) {
            __builtin_amdgcn_global_load_lds(
                (const __attribute__((address_space(1))) void*)(ag + (size_t)j * 16 * K),
                (__attribute__((address_space(3))) void*)(la + j * 16 * BK), 16, 0, 0);
            __builtin_amdgcn_global_load_lds(
                (const __attribute__((address_space(1))) void*)(bg + (size_t)j * 16 * K),
                (__attribute__((address_space(3))) void*)(lb + j * 16 * BK), 16, 0, 0);
        }
        ag += BK;
        bg += BK;
        __syncthreads();  // drains vmcnt: staged tile visible to all waves

        int4v af[4], bf[4];
        #pragma unroll
        for (int i = 0; i < 4; ++i) {
            af[i] = *(const int4v*)(ra + i * 16 * BK);
            bf[i] = *(const int4v*)(rb + i * 16 * BK);
        }
        #pragma unroll
        for (int i = 0; i < 4; ++i)
            #pragma unroll
            for (int j = 0; j < 4; ++j)
                acc[i][j] = __builtin_amdgcn_mfma_i32_16x16x64_i8(af[i], bf[j], acc[i][j], 0, 0, 0);

        __syncthreads();  // all LDS reads done before next staging overwrites
    }

    // Epilogue: C/D layout col(N)=lane&15, row(M)=(lane>>4)*4+reg
    // (m89-verified, dtype-independent per m121-m128).
    const int nl = lane & 15;
    const int quad = lane >> 4;
    float wv[4], bv[4];
    #pragma unroll
    for (int j = 0; j < 4; ++j) {
        wv[j] = wsc[bn + wn + j * 16 + nl];
        bv[j] = bias[bn + wn + j * 16 + nl];
    }
    #pragma unroll
    for (int i = 0; i < 4; ++i) {
        #pragma unroll
        for (int r = 0; r < 4; ++r) {
            const int row = bm + wm + i * 16 + quad * 4 + r;
            const float s = xs[row];
            float* crow = C + (size_t)row * N + bn + wn + nl;
            #pragma unroll
            for (int j = 0; j < 4; ++j)
                crow[j * 16] = (float)acc[i][j][r] * s * wv[j] + bv[j];
        }
    }
}

// ---------------------------------------------------------------------------
extern "C" void kernel_launch(void* const* d_in, const int* in_sizes, int n_in,
                              void* d_out, int out_size, void* d_ws, size_t ws_size,
                              hipStream_t stream) {
    const float* x = (const float*)d_in[0];
    const int* wq32 = (const int*)d_in[1];  // harness passes integers as int32!
    const float* wscale = (const float*)d_in[2];
    const float* bias = (const float*)d_in[3];
    float* out = (float*)d_out;

    const int d_out_dim = in_sizes[2];             // 4096 (weight_scale length)
    const int d_in_dim = in_sizes[1] / d_out_dim;  // 4096
    const int T = in_sizes[0] / d_in_dim;          // 8192 tokens

    // Workspace: [packed weights][x_q][x_scale]
    const size_t wbytes = (size_t)d_out_dim * d_in_dim;
    signed char* w8 = (signed char*)d_ws;
    signed char* xq = (signed char*)d_ws + wbytes;
    float* xscl = (float*)((char*)d_ws + wbytes + (size_t)T * d_in_dim);

    const long n4 = (long)d_out_dim * d_in_dim / 4;
    pack_w_kernel<<<(int)((n4 + 255) / 256), 256, 0, stream>>>(wq32, (int*)w8, n4);

    if (d_in_dim == 4096) {
        quant_kernel<4><<<T, 256, 0, stream>>>(x, xq, xscl, d_in_dim);
    } else {
        quant_kernel<8><<<T, 256, 0, stream>>>(x, xq, xscl, d_in_dim);
    }

    dim3 grid(d_out_dim / BN, T / BM);
    gemm_i8_kernel<<<grid, 256, 0, stream>>>(xq, w8, xscl, wscale, bias, out,
                                             T, d_out_dim, d_in_dim);
}